// Round 2
// baseline (823.528 us; speedup 1.0000x reference)
//
#include <hip/hip_runtime.h>

typedef __bf16 bf16;
typedef __attribute__((ext_vector_type(8))) __bf16 bf16x8;
typedef __attribute__((ext_vector_type(4))) float f32x4;

#define MFMA(a, b, c) __builtin_amdgcn_mfma_f32_16x16x32_bf16(a, b, c, 0, 0, 0)

constexpr int T_ = 2048, B_ = 2, E_ = 1024, H_ = 16, HD = 64;
constexpr int BH = B_ * H_;          // 32
constexpr int M_ = T_ * B_;          // 4096 tokens
constexpr size_t SEC = (size_t)BH * T_ * HD;  // 4194304 elems per q/k/v section

// convert 8 consecutive fp32 -> bf16x8
__device__ inline bf16x8 cvt8(const float* p) {
    const float4* q = (const float4*)p;
    float4 a = q[0], b = q[1];
    bf16x8 r;
    r[0] = (bf16)a.x; r[1] = (bf16)a.y; r[2] = (bf16)a.z; r[3] = (bf16)a.w;
    r[4] = (bf16)b.x; r[5] = (bf16)b.y; r[6] = (bf16)b.z; r[7] = (bf16)b.w;
    return r;
}

// ---------------------------------------------------------------------------
// Kernel A: qkv = g @ W_in^T + b_in (fp32 in), q *= 0.125, bf16 out scattered
// to [bh][t][d]. M=4096, N=3072, K=1024. 64x64 tile, BK=32, 4 waves.
// ---------------------------------------------------------------------------
__global__ __launch_bounds__(256) void qkv_gemm(const float* __restrict__ g,
                                                const float* __restrict__ Win,
                                                const float* __restrict__ bin,
                                                bf16* __restrict__ qkv) {
    __shared__ bf16 As[64][40];
    __shared__ bf16 Bs[64][40];
    const int tid = threadIdx.x;
    const int mbase = blockIdx.y * 64;
    const int nbase = blockIdx.x * 64;
    const int wave = tid >> 6, lane = tid & 63;
    const int quad = lane >> 4, l16 = lane & 15;
    const int wm = (wave >> 1) * 32, wn = (wave & 1) * 32;

    f32x4 acc[2][2] = {};
    const int lrow = tid >> 2, lcol = (tid & 3) * 8;
    const float* ga = g + (size_t)(mbase + lrow) * E_ + lcol;
    const float* gb = Win + (size_t)(nbase + lrow) * E_ + lcol;

    for (int kk = 0; kk < E_; kk += 32) {
        *(bf16x8*)&As[lrow][lcol] = cvt8(ga + kk);
        *(bf16x8*)&Bs[lrow][lcol] = cvt8(gb + kk);
        __syncthreads();
        bf16x8 a0 = *(const bf16x8*)&As[wm + l16][quad * 8];
        bf16x8 a1 = *(const bf16x8*)&As[wm + 16 + l16][quad * 8];
        bf16x8 b0 = *(const bf16x8*)&Bs[wn + l16][quad * 8];
        bf16x8 b1 = *(const bf16x8*)&Bs[wn + 16 + l16][quad * 8];
        acc[0][0] = MFMA(a0, b0, acc[0][0]);
        acc[0][1] = MFMA(a0, b1, acc[0][1]);
        acc[1][0] = MFMA(a1, b0, acc[1][0]);
        acc[1][1] = MFMA(a1, b1, acc[1][1]);
        __syncthreads();
    }
    for (int i = 0; i < 2; i++)
        for (int j = 0; j < 2; j++)
            for (int r = 0; r < 4; r++) {
                int grow = mbase + wm + i * 16 + quad * 4 + r;   // token index
                int gcol = nbase + wn + j * 16 + l16;            // 0..3071
                float v = acc[i][j][r] + bin[gcol];
                if (gcol < E_) v *= 0.125f;                      // q scaling
                int which = gcol >> 10, e = gcol & 1023;
                int h = e >> 6, d = e & 63;
                int t = grow >> 1, b = grow & 1;
                qkv[(size_t)which * SEC + (size_t)(b * H_ + h) * T_ * HD +
                    (size_t)t * HD + d] = (bf16)v;
            }
}

// ---------------------------------------------------------------------------
// Kernel B: attention for one (bh, 64-row q tile). Pass1: row sums of exp(S)
// (register-accumulated). Pass2: recompute S, write p (fp32, coalesced via
// LDS), accumulate O = P.V. O (bf16) overwrites this block's own q tile.
// ---------------------------------------------------------------------------
__global__ __launch_bounds__(256) void attn_kernel(bf16* __restrict__ qkv,
                                                   float* __restrict__ p_out) {
    __shared__ bf16 Qs[64][72];
    __shared__ bf16 Ks[64][72];
    __shared__ bf16 Vt[64][72];   // transposed V tile: [d][s]
    __shared__ float Ps[64][68];  // fp32 probs tile
    __shared__ float rsum[64];
    __shared__ float rinv[64];

    const int tid = threadIdx.x;
    const int qt = blockIdx.x, bh = blockIdx.y;
    const int wave = tid >> 6, lane = tid & 63;
    const int quad = lane >> 4, l16 = lane & 15;

    bf16* qb = qkv + (size_t)bh * T_ * HD + (size_t)qt * 64 * HD;
    const bf16* kb = qkv + SEC + (size_t)bh * T_ * HD;
    const bf16* vb = qkv + 2 * SEC + (size_t)bh * T_ * HD;

    for (int rep = 0; rep < 2; rep++) {
        int idx = tid + rep * 256;
        int r = idx >> 3, c = (idx & 7) * 8;
        *(uint4*)&Qs[r][c] = *(const uint4*)(qb + r * HD + c);
    }
    __syncthreads();

    bf16x8 aq0 = *(const bf16x8*)&Qs[wave * 16 + l16][quad * 8];
    bf16x8 aq1 = *(const bf16x8*)&Qs[wave * 16 + l16][32 + quad * 8];

    // ---- pass 1: row sums of exp(S), accumulated in registers ----
    float rs[4] = {0.f, 0.f, 0.f, 0.f};
    for (int kt = 0; kt < 32; kt++) {
        for (int rep = 0; rep < 2; rep++) {
            int idx = tid + rep * 256;
            int r = idx >> 3, c = (idx & 7) * 8;
            *(uint4*)&Ks[r][c] = *(const uint4*)(kb + (size_t)(kt * 64 + r) * HD + c);
        }
        __syncthreads();
        for (int jn = 0; jn < 4; jn++) {
            f32x4 s = {};
            bf16x8 b0 = *(const bf16x8*)&Ks[jn * 16 + l16][quad * 8];
            bf16x8 b1 = *(const bf16x8*)&Ks[jn * 16 + l16][32 + quad * 8];
            s = MFMA(aq0, b0, s);
            s = MFMA(aq1, b1, s);
            for (int r = 0; r < 4; r++) rs[r] += __expf(s[r]);
        }
        __syncthreads();
    }
    for (int off = 8; off; off >>= 1)
        for (int r = 0; r < 4; r++) rs[r] += __shfl_xor(rs[r], off, 16);
    if (l16 == 0)
        for (int r = 0; r < 4; r++) rsum[wave * 16 + quad * 4 + r] = rs[r];
    __syncthreads();
    if (tid < 64) rinv[tid] = 1.0f / rsum[tid];
    __syncthreads();

    float ri[4];
    for (int r = 0; r < 4; r++) ri[r] = rinv[wave * 16 + quad * 4 + r];

    f32x4 oacc[4] = {};
    // ---- pass 2: write p (fp32), accumulate O ----
    for (int kt = 0; kt < 32; kt++) {
        for (int rep = 0; rep < 2; rep++) {
            int idx = tid + rep * 256;
            int r = idx >> 3, c = (idx & 7) * 8;
            *(uint4*)&Ks[r][c] = *(const uint4*)(kb + (size_t)(kt * 64 + r) * HD + c);
            bf16x8 v = *(const bf16x8*)(vb + (size_t)(kt * 64 + r) * HD + c);
            for (int j = 0; j < 8; j++) Vt[c + j][r] = v[j];
        }
        __syncthreads();
        for (int jn = 0; jn < 4; jn++) {
            f32x4 s = {};
            bf16x8 b0 = *(const bf16x8*)&Ks[jn * 16 + l16][quad * 8];
            bf16x8 b1 = *(const bf16x8*)&Ks[jn * 16 + l16][32 + quad * 8];
            s = MFMA(aq0, b0, s);
            s = MFMA(aq1, b1, s);
            for (int r = 0; r < 4; r++)
                Ps[quad * 4 + r + wave * 16][jn * 16 + l16] = __expf(s[r]) * ri[r];
        }
        __syncthreads();
        // coalesced fp32 p store from LDS
        float* pb = p_out + (size_t)bh * T_ * T_ + (size_t)(qt * 64) * T_ + kt * 64;
        for (int rep = 0; rep < 4; rep++) {
            int idx = tid + rep * 256;
            int r = idx >> 4, c = (idx & 15) * 4;
            *(float4*)(pb + (size_t)r * T_ + c) = *(const float4*)&Ps[r][c];
        }
        // O += P x V^T : A-fragment from fp32 Ps via convert
        bf16x8 a0 = cvt8(&Ps[wave * 16 + l16][quad * 8]);
        bf16x8 a1 = cvt8(&Ps[wave * 16 + l16][32 + quad * 8]);
        for (int jb = 0; jb < 4; jb++) {
            bf16x8 b0 = *(const bf16x8*)&Vt[jb * 16 + l16][quad * 8];
            bf16x8 b1 = *(const bf16x8*)&Vt[jb * 16 + l16][32 + quad * 8];
            oacc[jb] = MFMA(a0, b0, oacc[jb]);
            oacc[jb] = MFMA(a1, b1, oacc[jb]);
        }
        __syncthreads();
    }

    // write O over this block's own q tile (only this block ever reads it)
    for (int jb = 0; jb < 4; jb++)
        for (int r = 0; r < 4; r++)
            qb[(size_t)(wave * 16 + quad * 4 + r) * HD + jb * 16 + l16] =
                (bf16)oacc[jb][r];
}

// ---------------------------------------------------------------------------
// Kernel C: out = attn @ W_out^T + b_out (fp32 out). M=4096, N=1024, K=1024.
// A (bf16) gathered from head layout [bh][t][d] (= q section of ws).
// ---------------------------------------------------------------------------
__global__ __launch_bounds__(256) void out_gemm(const bf16* __restrict__ attn,
                                                const float* __restrict__ Wout,
                                                const float* __restrict__ bout,
                                                float* __restrict__ out) {
    __shared__ bf16 As[64][40];
    __shared__ bf16 Bs[64][40];
    const int tid = threadIdx.x;
    const int mbase = blockIdx.y * 64;
    const int nbase = blockIdx.x * 64;
    const int wave = tid >> 6, lane = tid & 63;
    const int quad = lane >> 4, l16 = lane & 15;
    const int wm = (wave >> 1) * 32, wn = (wave & 1) * 32;

    f32x4 acc[2][2] = {};
    const int lrow = tid >> 2, lcol = (tid & 3) * 8;
    const int arow = mbase + lrow;
    const int tok_t = arow >> 1, tok_b = arow & 1;
    const float* gb = Wout + (size_t)(nbase + lrow) * E_ + lcol;

    for (int kk = 0; kk < E_; kk += 32) {
        int kc = kk + lcol;
        int h = kc >> 6, d = kc & 63;
        *(uint4*)&As[lrow][lcol] = *(const uint4*)(attn +
            (size_t)(tok_b * H_ + h) * T_ * HD + (size_t)tok_t * HD + d);
        *(bf16x8*)&Bs[lrow][lcol] = cvt8(gb + kk);
        __syncthreads();
        bf16x8 a0 = *(const bf16x8*)&As[wm + l16][quad * 8];
        bf16x8 a1 = *(const bf16x8*)&As[wm + 16 + l16][quad * 8];
        bf16x8 b0 = *(const bf16x8*)&Bs[wn + l16][quad * 8];
        bf16x8 b1 = *(const bf16x8*)&Bs[wn + 16 + l16][quad * 8];
        acc[0][0] = MFMA(a0, b0, acc[0][0]);
        acc[0][1] = MFMA(a0, b1, acc[0][1]);
        acc[1][0] = MFMA(a1, b0, acc[1][0]);
        acc[1][1] = MFMA(a1, b1, acc[1][1]);
        __syncthreads();
    }
    for (int i = 0; i < 2; i++)
        for (int j = 0; j < 2; j++)
            for (int r = 0; r < 4; r++) {
                int grow = mbase + wm + i * 16 + quad * 4 + r;
                int gcol = nbase + wn + j * 16 + l16;
                out[(size_t)grow * E_ + gcol] = acc[i][j][r] + bout[gcol];
            }
}

extern "C" void kernel_launch(void* const* d_in, const int* in_sizes, int n_in,
                              void* d_out, int out_size, void* d_ws, size_t ws_size,
                              hipStream_t stream) {
    const float* g = (const float*)d_in[0];
    const float* Win = (const float*)d_in[1];
    const float* bin = (const float*)d_in[2];
    const float* Wout = (const float*)d_in[3];
    const float* bout = (const float*)d_in[4];

    float* out = (float*)d_out;               // 4,194,304 fp32
    float* p = out + (size_t)M_ * E_;         // 134,217,728 fp32
    bf16* qkv_ws = (bf16*)d_ws;               // 3 * SEC bf16 = 24 MB

    qkv_gemm<<<dim3(48, 64), 256, 0, stream>>>(g, Win, bin, qkv_ws);
    attn_kernel<<<dim3(32, 32), 256, 0, stream>>>(qkv_ws, p);
    out_gemm<<<dim3(16, 64), 256, 0, stream>>>(qkv_ws, Wout, bout, out);
}